// Round 1
// baseline (314.830 us; speedup 1.0000x reference)
//
#include <hip/hip_runtime.h>

typedef short short8 __attribute__((ext_vector_type(8)));
typedef float floatx4 __attribute__((ext_vector_type(4)));

__device__ __forceinline__ unsigned short f2bf(float f) {
  unsigned u = __float_as_uint(f);
  u += 0x7FFFu + ((u >> 16) & 1u);   // round-to-nearest-even
  return (unsigned short)(u >> 16);
}

// ---------------------------------------------------------------------------
// Kernel 1a: partial projections. part[(which*8+dchunk)*512 + n][c] = sum over
// 256 d of im[n][d] * W[d][c].  grid (8 dchunks, 16 rowtiles, 2 which), 256 thr
// ---------------------------------------------------------------------------
__global__ __launch_bounds__(256) void proj_partial(
    const float* __restrict__ im_q, const float* __restrict__ im_k,
    const float* __restrict__ Wq, const float* __restrict__ Wk,
    float* __restrict__ part, int* __restrict__ cnt) {
  __shared__ float imS[32 * 260];  // [r][d], stride 260 (pad: conflict-free b128 writes)
  const int t = threadIdx.x;
  if (blockIdx.x == 0 && blockIdx.y == 0 && blockIdx.z == 0 && t < 4) cnt[t] = 0;
  const int which = blockIdx.z;
  const float* __restrict__ im = which ? im_k : im_q;
  const float* __restrict__ W  = which ? Wk : Wq;
  const int d0 = blockIdx.x * 256;
  const int row0 = blockIdx.y * 32;
  {
    const int dd0 = (t & 63) * 4;
    const int rb = t >> 6;
#pragma unroll
    for (int p = 0; p < 8; ++p) {
      const int r = rb + p * 4;
      const float4 v = *(const float4*)(im + (size_t)(row0 + r) * 2048 + d0 + dd0);
      *(float4*)(imS + r * 260 + dd0) = v;
    }
  }
  __syncthreads();
  const int c4 = (t & 31) * 4;   // 32 col groups * 4 = 128 cols
  const int r4 = (t >> 5) * 4;   // 8 row groups * 4 = 32 rows
  float acc[4][4] = {};
  const float* __restrict__ Wp = W + (size_t)d0 * 128 + c4;
#pragma unroll 4
  for (int d = 0; d < 256; ++d) {
    const float4 w = *(const float4*)(Wp + (size_t)d * 128);
    float a[4];
#pragma unroll
    for (int rr = 0; rr < 4; ++rr) a[rr] = imS[(r4 + rr) * 260 + d];  // LDS broadcast
#pragma unroll
    for (int rr = 0; rr < 4; ++rr) {
      acc[rr][0] += a[rr] * w.x;
      acc[rr][1] += a[rr] * w.y;
      acc[rr][2] += a[rr] * w.z;
      acc[rr][3] += a[rr] * w.w;
    }
  }
#pragma unroll
  for (int rr = 0; rr < 4; ++rr) {
    float4 v = make_float4(acc[rr][0], acc[rr][1], acc[rr][2], acc[rr][3]);
    *(float4*)(part + ((size_t)(which * 8 + blockIdx.x) * 512 + row0 + r4 + rr) * 128 + c4) = v;
  }
}

// ---------------------------------------------------------------------------
// Kernel 1b: reduce partials, normalize, l_pos, q->bf16, group lists, labels=0
// grid 512 blocks x 128 threads (one block per sample n)
// ---------------------------------------------------------------------------
__global__ __launch_bounds__(128) void finalize(
    const float* __restrict__ part, const int* __restrict__ label,
    unsigned short* __restrict__ qbf, int* __restrict__ cnt,
    int* __restrict__ rows, float* __restrict__ out) {
  const int n = blockIdx.x, c = threadIdx.x;
  float qraw = 0.f, kraw = 0.f;
#pragma unroll
  for (int ch = 0; ch < 8; ++ch) {
    qraw += part[((size_t)ch * 512 + n) * 128 + c];
    kraw += part[((size_t)(8 + ch) * 512 + n) * 128 + c];
  }
  float sq = qraw * qraw, sk = kraw * kraw, dt = qraw * kraw;
#pragma unroll
  for (int off = 32; off > 0; off >>= 1) {
    sq += __shfl_down(sq, off, 64);
    sk += __shfl_down(sk, off, 64);
    dt += __shfl_down(dt, off, 64);
  }
  __shared__ float sh[3][2];
  const int lane = c & 63, wv = c >> 6;
  if (lane == 0) { sh[0][wv] = sq; sh[1][wv] = sk; sh[2][wv] = dt; }
  __syncthreads();
  const float tsq = sh[0][0] + sh[0][1];
  const float tsk = sh[1][0] + sh[1][1];
  const float tdt = sh[2][0] + sh[2][1];
  const float nq = fmaxf(sqrtf(tsq), 1e-12f);
  const float nk = fmaxf(sqrtf(tsk), 1e-12f);
  qbf[n * 128 + c] = f2bf(qraw / nq);
  if (c == 0) {
    out[(size_t)n * 65537] = tdt / (nq * nk) * (1.0f / 0.07f);   // l_pos / T
    ((int*)out)[(size_t)512 * 65537 + n] = 0;                    // labels
    int g = ((label[n] - 1) % 4 + 4) % 4;                        // (label-1) mod 4
    int pos = atomicAdd(cnt + g, 1);
    rows[g * 512 + pos] = n;
  }
}

// ---------------------------------------------------------------------------
// Kernel 2: grouped GEMM l_neg = Q_g @ queues[g], bf16 MFMA, /T on epilogue.
// grid (512 col tiles, 4 groups) x 256 threads.
// ---------------------------------------------------------------------------
__global__ __launch_bounds__(256) void moco_lneg(
    const float* __restrict__ queues, const unsigned short* __restrict__ qbf,
    const int* __restrict__ cnt, const int* __restrict__ rows,
    float* __restrict__ out) {
  __shared__ unsigned short Bs[128 * 130];  // [j][c] bf16, stride 130
  __shared__ unsigned short Qs[128 * 130];  // [m][k] bf16, stride 130
  __shared__ int rowsS[128];
  const int g = blockIdx.y;
  const int Mg = cnt[g];
  if (Mg == 0) return;
  const int t = threadIdx.x;
  const int j0 = blockIdx.x * 128;
  // ---- stage B tile (fp32 global -> bf16 LDS, transposed) ----
  {
    const int j = t & 127;
    const int cb = (t >> 7) * 64;
    const float* __restrict__ qb = queues + (size_t)g * 128 * 65536 + j0 + j;
#pragma unroll 8
    for (int p = 0; p < 32; ++p) {
      const int c = cb + p * 2;
      const float f0 = qb[(size_t)c * 65536];
      const float f1 = qb[(size_t)(c + 1) * 65536];
      const unsigned u = (unsigned)f2bf(f0) | ((unsigned)f2bf(f1) << 16);
      *(unsigned*)(Bs + j * 130 + c) = u;   // banks = j + const : conflict-free
    }
  }
  const int lane = t & 63, wave = t >> 6;
  const int qd = lane >> 4, l16 = lane & 15;
  const float invT = 1.0f / 0.07f;
  for (int chunk0 = 0; chunk0 < Mg; chunk0 += 128) {
    __syncthreads();   // prior chunk done reading Qs; also fences Bs staging
    const int valid = min(Mg - chunk0, 128);
    if (t < 128) rowsS[t] = (t < valid) ? rows[g * 512 + chunk0 + t] : 0;
    {
      const int m = t >> 1, half = (t & 1) * 64;
      if (m < valid) {
        const int rg = rows[g * 512 + chunk0 + m];
        const unsigned* __restrict__ src = (const unsigned*)(qbf + rg * 128 + half);
#pragma unroll
        for (int i = 0; i < 32; ++i)
          *(unsigned*)(Qs + m * 130 + half + i * 2) = src[i];
      } else {
#pragma unroll
        for (int i = 0; i < 32; ++i)
          *(unsigned*)(Qs + m * 130 + half + i * 2) = 0u;
      }
    }
    __syncthreads();
    floatx4 acc[8][2];
#pragma unroll
    for (int rb = 0; rb < 8; ++rb) {
      floatx4 z = {0.f, 0.f, 0.f, 0.f};
      acc[rb][0] = z; acc[rb][1] = z;
    }
#pragma unroll
    for (int kk = 0; kk < 4; ++kk) {
      const int k0 = kk * 32 + qd * 8;
      short8 bfrag[2];
#pragma unroll
      for (int s = 0; s < 2; ++s) {
        const unsigned* p = (const unsigned*)(Bs + ((wave * 2 + s) * 16 + l16) * 130 + k0);
        unsigned* d = (unsigned*)&bfrag[s];
        d[0] = p[0]; d[1] = p[1]; d[2] = p[2]; d[3] = p[3];
      }
#pragma unroll
      for (int rb = 0; rb < 8; ++rb) {
        const unsigned* p = (const unsigned*)(Qs + (rb * 16 + l16) * 130 + k0);
        short8 afrag;
        unsigned* d = (unsigned*)&afrag;
        d[0] = p[0]; d[1] = p[1]; d[2] = p[2]; d[3] = p[3];
        acc[rb][0] = __builtin_amdgcn_mfma_f32_16x16x32_bf16(afrag, bfrag[0], acc[rb][0], 0, 0, 0);
        acc[rb][1] = __builtin_amdgcn_mfma_f32_16x16x32_bf16(afrag, bfrag[1], acc[rb][1], 0, 0, 0);
      }
    }
    // ---- epilogue: C/D layout col=lane&15, row=quad*4+reg ----
#pragma unroll
    for (int rb = 0; rb < 8; ++rb) {
#pragma unroll
      for (int r = 0; r < 4; ++r) {
        const int ml = rb * 16 + qd * 4 + r;
        if (ml < valid) {
          const size_t base = (size_t)rowsS[ml] * 65537 + 1 + j0;
#pragma unroll
          for (int s = 0; s < 2; ++s)
            out[base + (wave * 2 + s) * 16 + l16] = acc[rb][s][r] * invT;
        }
      }
    }
  }
}

extern "C" void kernel_launch(void* const* d_in, const int* in_sizes, int n_in,
                              void* d_out, int out_size, void* d_ws, size_t ws_size,
                              hipStream_t stream) {
  const float* im_q   = (const float*)d_in[0];
  const float* im_k   = (const float*)d_in[1];
  const float* Wq     = (const float*)d_in[2];
  const float* Wk     = (const float*)d_in[3];
  const float* queues = (const float*)d_in[4];
  const int*   label  = (const int*)d_in[5];
  float* out = (float*)d_out;

  char* ws = (char*)d_ws;
  float* part = (float*)ws;                                   // 2*8*512*128 f32 = 4 MB
  unsigned short* qbf = (unsigned short*)(ws + (4u << 20));   // 512*128 bf16 = 128 KB
  int* cnt  = (int*)(ws + (4u << 20) + (128u << 10));         // 4 ints
  int* rows = cnt + 4;                                        // 4*512 ints

  proj_partial<<<dim3(8, 16, 2), 256, 0, stream>>>(im_q, im_k, Wq, Wk, part, cnt);
  finalize<<<512, 128, 0, stream>>>(part, label, qbf, cnt, rows, out);
  moco_lneg<<<dim3(512, 4), 256, 0, stream>>>(queues, qbf, cnt, rows, out);
}